// Round 1
// baseline (1301.752 us; speedup 1.0000x reference)
//
#include <hip/hip_runtime.h>

#define MESH  128
#define MESH2 16384
#define MESH3 2097152
#define NPART MESH3
#define TILE  16

__device__ __forceinline__ float2 cmul(float2 a, float2 b) {
    return make_float2(a.x * b.x - a.y * b.y, a.x * b.y + a.y * b.x);
}

// In-place 1D FFT of length 128 along AXIS (2=z contiguous, 1=y stride 128,
// 0=x stride 16384). Forward = DIF (natural in -> bit-reversed out),
// Inverse = DIT (bit-reversed in -> natural out), twiddles conjugated.
// No 1/N scaling here (folded into filter).
template <int AXIS, bool INV>
__global__ __launch_bounds__(256) void fft_pass(float2* __restrict__ data) {
    __shared__ float2 s[MESH][TILE + 1];  // +1 pad: breaks power-of-2 bank stride
    __shared__ float2 tw[64];
    const int t = threadIdx.x;
    if (t < 64) {
        float sv, cv;
        sincospif(-(float)t / 64.0f, &sv, &cv);  // exp(-2*pi*i*t/128)
        tw[t] = make_float2(cv, INV ? -sv : sv);
    }

    int base = 0, estride = 1;
    if (AXIS == 2) {
        base = blockIdx.x * (TILE * MESH);   // 16 contiguous lines
        for (int i = t; i < MESH * TILE; i += 256)
            s[i & 127][i >> 7] = data[base + i];
    } else {
        const int outer = blockIdx.x >> 3;          // fixed ix (AXIS=1) / iy (AXIS=0)
        const int z0 = (blockIdx.x & 7) * TILE;     // contiguous z tile
        estride = (AXIS == 1) ? MESH : MESH2;
        base = (AXIS == 1) ? (outer * MESH2 + z0) : (outer * MESH + z0);
        for (int i = t; i < MESH * TILE; i += 256) {
            const int l = i & 15, e = i >> 4;
            s[e][l] = data[base + e * estride + l];
        }
    }
    __syncthreads();

    const int l  = t & 15;   // line within tile
    const int bb = t >> 4;   // butterfly group 0..15 (x4 iters = 64 butterflies)
    if (!INV) {
        #pragma unroll
        for (int st = 0; st < 7; ++st) {
            const int logh = 6 - st;
            const int half = 1 << logh;
            #pragma unroll
            for (int it = 0; it < 4; ++it) {
                const int b  = bb + (it << 4);
                const int j  = b & (half - 1);
                const int g  = b >> logh;
                const int i0 = (g << (logh + 1)) + j;
                const int i1 = i0 + half;
                float2 u = s[i0][l], v = s[i1][l];
                float2 d = make_float2(u.x - v.x, u.y - v.y);
                s[i0][l] = make_float2(u.x + v.x, u.y + v.y);
                s[i1][l] = cmul(d, tw[j << st]);
            }
            __syncthreads();
        }
    } else {
        #pragma unroll
        for (int st = 0; st < 7; ++st) {
            const int half = 1 << st;
            #pragma unroll
            for (int it = 0; it < 4; ++it) {
                const int b  = bb + (it << 4);
                const int j  = b & (half - 1);
                const int g  = b >> st;
                const int i0 = (g << (st + 1)) + j;
                const int i1 = i0 + half;
                float2 u = s[i0][l];
                float2 v = cmul(s[i1][l], tw[j << (6 - st)]);
                s[i0][l] = make_float2(u.x + v.x, u.y + v.y);
                s[i1][l] = make_float2(u.x - v.x, u.y - v.y);
            }
            __syncthreads();
        }
    }

    if (AXIS == 2) {
        for (int i = t; i < MESH * TILE; i += 256)
            data[base + i] = s[i & 127][i >> 7];
    } else {
        for (int i = t; i < MESH * TILE; i += 256) {
            const int l2 = i & 15, e = i >> 4;
            data[base + e * estride + l2] = s[e][l2];
        }
    }
}

// k-space filter. Input A = fftn(delta) in per-axis bit-reversed storage.
// Writes A <- (ky - i*kx) * pot, B <- -i*kz * pot,  pot = delta_k * (-1/kk)
// * exp(-KL^2/kk - kk^2/KS^4) / MESH^3  (zero at k=0).
__global__ __launch_bounds__(256) void filter_kernel(float2* __restrict__ A,
                                                     float2* __restrict__ B) {
    const int idx = blockIdx.x * 256 + threadIdx.x;
    const int cz = idx & 127;
    const int cy = (idx >> 7) & 127;
    const int cx = idx >> 14;
    const int jx = (int)(__brev((unsigned)cx) >> 25);  // bitrev7
    const int jy = (int)(__brev((unsigned)cy) >> 25);
    const int jz = (int)(__brev((unsigned)cz) >> 25);
    const float c = 6.28318530717958647692f / 128.0f;
    const float kx = c * (float)(jx < 64 ? jx : jx - 128);
    const float ky = c * (float)(jy < 64 ? jy : jy - 128);
    const float kz = c * (float)(jz < 64 ? jz : jz - 128);
    const float kk = kx * kx + ky * ky + kz * kz;
    float2 a = A[idx];
    float2 av = make_float2(0.f, 0.f), bv = make_float2(0.f, 0.f);
    if (kk > 0.0f) {
        const float inv_kk = 1.0f / kk;
        // KL=0.3 -> KL^2=0.09 ; KS=1 -> KS^4=1
        const float rng = __expf(-0.09f * inv_kk - kk * kk);
        const float sc  = -inv_kk * rng * (1.0f / 2097152.0f);  // includes 1/M^3
        const float pr = a.x * sc, pi = a.y * sc;
        av = make_float2(ky * pr + kx * pi, ky * pi - kx * pr);  // (ky - i kx)*pot
        bv = make_float2(kz * pi, -kz * pr);                     // -i kz * pot
    }
    A[idx] = av;
    B[idx] = bv;
}

// CIC scatter: deposit trilinear weights into real parts of complex grid A.
__global__ __launch_bounds__(256) void paint_kernel(const float* __restrict__ pos,
                                                    float* __restrict__ grid /* A as floats */) {
    const int n = blockIdx.x * 256 + threadIdx.x;
    if (n >= NPART) return;
    const float px = pos[3 * n], py = pos[3 * n + 1], pz = pos[3 * n + 2];
    const int ix0 = (int)floorf(px), iy0 = (int)floorf(py), iz0 = (int)floorf(pz);
    const float fx = px - (float)ix0, fy = py - (float)iy0, fz = pz - (float)iz0;
    const int xs[2] = {ix0 & 127, (ix0 + 1) & 127};
    const int ys[2] = {iy0 & 127, (iy0 + 1) & 127};
    const int zs[2] = {iz0 & 127, (iz0 + 1) & 127};
    const float wx[2] = {1.0f - fx, fx};
    const float wy[2] = {1.0f - fy, fy};
    const float wz[2] = {1.0f - fz, fz};
    #pragma unroll
    for (int dx = 0; dx < 2; ++dx)
        #pragma unroll
        for (int dy = 0; dy < 2; ++dy)
            #pragma unroll
            for (int dz = 0; dz < 2; ++dz) {
                const int cell = ((xs[dx] << 7) + ys[dy]) * 128 + zs[dz];
                atomicAdd(grid + 2 * cell, wx[dx] * wy[dy] * wz[dz]);
            }
}

// CIC gather of forces (fx=Re A, fy=Im A, fz=Re B) + velocity boost + pos copy.
__global__ __launch_bounds__(256) void readout_kernel(const float* __restrict__ pos,
                                                      const float* __restrict__ vel,
                                                      const float* __restrict__ fdf,
                                                      const float2* __restrict__ A,
                                                      const float* __restrict__ Bf,
                                                      float* __restrict__ out) {
    const int n = blockIdx.x * 256 + threadIdx.x;
    if (n >= NPART) return;
    const float px = pos[3 * n], py = pos[3 * n + 1], pz = pos[3 * n + 2];
    const int ix0 = (int)floorf(px), iy0 = (int)floorf(py), iz0 = (int)floorf(pz);
    const float fxr = px - (float)ix0, fyr = py - (float)iy0, fzr = pz - (float)iz0;
    const int xs[2] = {ix0 & 127, (ix0 + 1) & 127};
    const int ys[2] = {iy0 & 127, (iy0 + 1) & 127};
    const int zs[2] = {iz0 & 127, (iz0 + 1) & 127};
    const float wx[2] = {1.0f - fxr, fxr};
    const float wy[2] = {1.0f - fyr, fyr};
    const float wz[2] = {1.0f - fzr, fzr};
    float fx = 0.f, fy = 0.f, fz = 0.f;
    #pragma unroll
    for (int dx = 0; dx < 2; ++dx)
        #pragma unroll
        for (int dy = 0; dy < 2; ++dy)
            #pragma unroll
            for (int dz = 0; dz < 2; ++dz) {
                const int cell = ((xs[dx] << 7) + ys[dy]) * 128 + zs[dz];
                const float w = wx[dx] * wy[dy] * wz[dz];
                const float2 a = A[cell];
                fx += w * a.x;
                fy += w * a.y;
                fz += w * Bf[2 * cell];
            }
    const float sc = 0.2f / fdf[0];
    out[3 * n + 0] = px;
    out[3 * n + 1] = py;
    out[3 * n + 2] = pz;
    out[3 * NPART + 3 * n + 0] = vel[3 * n + 0] + fx * sc;
    out[3 * NPART + 3 * n + 1] = vel[3 * n + 1] + fy * sc;
    out[3 * NPART + 3 * n + 2] = vel[3 * n + 2] + fz * sc;
}

extern "C" void kernel_launch(void* const* d_in, const int* in_sizes, int n_in,
                              void* d_out, int out_size, void* d_ws, size_t ws_size,
                              hipStream_t stream) {
    const float* pos = (const float*)d_in[0];
    const float* vel = (const float*)d_in[1];
    const float* fdf = (const float*)d_in[2];
    float* out = (float*)d_out;

    float2* A = (float2*)d_ws;          // 16 MB complex grid
    float2* B = A + MESH3;              // 16 MB complex grid

    // zero A (paint target; ws is poisoned before every call)
    hipMemsetAsync(A, 0, sizeof(float2) * (size_t)MESH3, stream);

    paint_kernel<<<NPART / 256, 256, 0, stream>>>(pos, (float*)A);

    // forward 3D FFT (DIF: natural -> bit-reversed per axis)
    fft_pass<2, false><<<1024, 256, 0, stream>>>(A);
    fft_pass<1, false><<<1024, 256, 0, stream>>>(A);
    fft_pass<0, false><<<1024, 256, 0, stream>>>(A);

    filter_kernel<<<MESH3 / 256, 256, 0, stream>>>(A, B);

    // inverse 3D FFTs (DIT: bit-reversed -> natural), A carries (fx,fy), B carries fz
    fft_pass<0, true><<<1024, 256, 0, stream>>>(A);
    fft_pass<1, true><<<1024, 256, 0, stream>>>(A);
    fft_pass<2, true><<<1024, 256, 0, stream>>>(A);
    fft_pass<0, true><<<1024, 256, 0, stream>>>(B);
    fft_pass<1, true><<<1024, 256, 0, stream>>>(B);
    fft_pass<2, true><<<1024, 256, 0, stream>>>(B);

    readout_kernel<<<NPART / 256, 256, 0, stream>>>(pos, vel, fdf, A, (const float*)B, out);
}

// Round 2
// 428.362 us; speedup vs baseline: 3.0389x; 3.0389x over previous
//
#include <hip/hip_runtime.h>

#define MESH  128
#define MESH2 16384
#define MESH3 2097152
#define NPART MESH3
#define TILE  16
typedef unsigned int u32;
typedef unsigned long long u64;

// packed particle record (8B):
//  bits [0,7)   iz
//  bits [7,9)   lx (ix & 3)
//  bits [9,11)  ly (iy & 3)
//  bits [11,21) qx (frac x, 10-bit)
//  bits [21,31) qy
//  bits [31,41) qz
//  bits [41,62) n  (original particle index, 21 bits)

__device__ __forceinline__ float2 cmul(float2 a, float2 b) {
    return make_float2(a.x * b.x - a.y * b.y, a.x * b.y + a.y * b.x);
}

template <int AXIS, bool INV>
__global__ __launch_bounds__(256) void fft_pass(float2* __restrict__ data) {
    __shared__ float2 s[MESH][TILE + 1];
    __shared__ float2 tw[64];
    const int t = threadIdx.x;
    if (t < 64) {
        float sv, cv;
        sincospif(-(float)t / 64.0f, &sv, &cv);
        tw[t] = make_float2(cv, INV ? -sv : sv);
    }

    int base = 0, estride = 1;
    if (AXIS == 2) {
        base = blockIdx.x * (TILE * MESH);
        for (int i = t; i < MESH * TILE; i += 256)
            s[i & 127][i >> 7] = data[base + i];
    } else {
        const int outer = blockIdx.x >> 3;
        const int z0 = (blockIdx.x & 7) * TILE;
        estride = (AXIS == 1) ? MESH : MESH2;
        base = (AXIS == 1) ? (outer * MESH2 + z0) : (outer * MESH + z0);
        for (int i = t; i < MESH * TILE; i += 256) {
            const int l = i & 15, e = i >> 4;
            s[e][l] = data[base + e * estride + l];
        }
    }
    __syncthreads();

    const int l  = t & 15;
    const int bb = t >> 4;
    if (!INV) {
        #pragma unroll
        for (int st = 0; st < 7; ++st) {
            const int logh = 6 - st;
            const int half = 1 << logh;
            #pragma unroll
            for (int it = 0; it < 4; ++it) {
                const int b  = bb + (it << 4);
                const int j  = b & (half - 1);
                const int g  = b >> logh;
                const int i0 = (g << (logh + 1)) + j;
                const int i1 = i0 + half;
                float2 u = s[i0][l], v = s[i1][l];
                float2 d = make_float2(u.x - v.x, u.y - v.y);
                s[i0][l] = make_float2(u.x + v.x, u.y + v.y);
                s[i1][l] = cmul(d, tw[j << st]);
            }
            __syncthreads();
        }
    } else {
        #pragma unroll
        for (int st = 0; st < 7; ++st) {
            const int half = 1 << st;
            #pragma unroll
            for (int it = 0; it < 4; ++it) {
                const int b  = bb + (it << 4);
                const int j  = b & (half - 1);
                const int g  = b >> st;
                const int i0 = (g << (st + 1)) + j;
                const int i1 = i0 + half;
                float2 u = s[i0][l];
                float2 v = cmul(s[i1][l], tw[j << (6 - st)]);
                s[i0][l] = make_float2(u.x + v.x, u.y + v.y);
                s[i1][l] = make_float2(u.x - v.x, u.y - v.y);
            }
            __syncthreads();
        }
    }

    if (AXIS == 2) {
        for (int i = t; i < MESH * TILE; i += 256)
            data[base + i] = s[i & 127][i >> 7];
    } else {
        for (int i = t; i < MESH * TILE; i += 256) {
            const int l2 = i & 15, e = i >> 4;
            data[base + e * estride + l2] = s[e][l2];
        }
    }
}

__global__ __launch_bounds__(256) void fft_z_fwd_real(const float* __restrict__ Rin,
                                                      float2* __restrict__ out) {
    __shared__ float2 s[MESH][TILE + 1];
    __shared__ float2 tw[64];
    const int t = threadIdx.x;
    if (t < 64) {
        float sv, cv;
        sincospif(-(float)t / 64.0f, &sv, &cv);
        tw[t] = make_float2(cv, sv);
    }
    const int base = blockIdx.x * (TILE * MESH);
    for (int i = t; i < MESH * TILE; i += 256)
        s[i & 127][i >> 7] = make_float2(Rin[base + i], 0.0f);
    __syncthreads();

    const int l  = t & 15;
    const int bb = t >> 4;
    #pragma unroll
    for (int st = 0; st < 7; ++st) {
        const int logh = 6 - st;
        const int half = 1 << logh;
        #pragma unroll
        for (int it = 0; it < 4; ++it) {
            const int b  = bb + (it << 4);
            const int j  = b & (half - 1);
            const int g  = b >> logh;
            const int i0 = (g << (logh + 1)) + j;
            const int i1 = i0 + half;
            float2 u = s[i0][l], v = s[i1][l];
            float2 d = make_float2(u.x - v.x, u.y - v.y);
            s[i0][l] = make_float2(u.x + v.x, u.y + v.y);
            s[i1][l] = cmul(d, tw[j << st]);
        }
        __syncthreads();
    }
    for (int i = t; i < MESH * TILE; i += 256)
        out[base + i] = s[i & 127][i >> 7];
}

__global__ __launch_bounds__(256) void filter_kernel(float2* __restrict__ A,
                                                     float2* __restrict__ B) {
    const int idx = blockIdx.x * 256 + threadIdx.x;
    const int cz = idx & 127;
    const int cy = (idx >> 7) & 127;
    const int cx = idx >> 14;
    const int jx = (int)(__brev((unsigned)cx) >> 25);
    const int jy = (int)(__brev((unsigned)cy) >> 25);
    const int jz = (int)(__brev((unsigned)cz) >> 25);
    const float c = 6.28318530717958647692f / 128.0f;
    const float kx = c * (float)(jx < 64 ? jx : jx - 128);
    const float ky = c * (float)(jy < 64 ? jy : jy - 128);
    const float kz = c * (float)(jz < 64 ? jz : jz - 128);
    const float kk = kx * kx + ky * ky + kz * kz;
    float2 a = A[idx];
    float2 av = make_float2(0.f, 0.f), bv = make_float2(0.f, 0.f);
    if (kk > 0.0f) {
        const float inv_kk = 1.0f / kk;
        const float rng = __expf(-0.09f * inv_kk - kk * kk);  // KL^2=0.09, KS^4=1
        const float sc  = -inv_kk * rng * (1.0f / 2097152.0f);
        const float pr = a.x * sc, pi = a.y * sc;
        av = make_float2(ky * pr + kx * pi, ky * pi - kx * pr);
        bv = make_float2(kz * pi, -kz * pr);
    }
    A[idx] = av;
    B[idx] = bv;
}

__device__ __forceinline__ int bucket_of(float px, float py) {
    const int ix = ((int)floorf(px)) & 127;
    const int iy = ((int)floorf(py)) & 127;
    return ((ix >> 2) << 5) | (iy >> 2);
}

__global__ __launch_bounds__(256) void hist_kernel(const float* __restrict__ pos,
                                                   u32* __restrict__ cnt) {
    __shared__ u32 h[1024];
    const int t = threadIdx.x;
    for (int i = t; i < 1024; i += 256) h[i] = 0;
    __syncthreads();
    const int base_n = blockIdx.x * 8192;
    for (int it = 0; it < 32; ++it) {
        const int n = base_n + (it << 8) + t;
        atomicAdd(&h[bucket_of(pos[3 * n], pos[3 * n + 1])], 1u);
    }
    __syncthreads();
    for (int i = t; i < 1024; i += 256)
        if (h[i]) atomicAdd(&cnt[i], h[i]);
}

__global__ __launch_bounds__(1024) void scan_kernel(const u32* __restrict__ cnt,
                                                    u32* __restrict__ offsets,
                                                    u32* __restrict__ cursors) {
    __shared__ u32 tmp[1024];
    const int t = threadIdx.x;
    const u32 x = cnt[t];
    tmp[t] = x;
    __syncthreads();
    for (int off = 1; off < 1024; off <<= 1) {
        const u32 v = (t >= off) ? tmp[t - off] : 0u;
        __syncthreads();
        tmp[t] += v;
        __syncthreads();
    }
    const u32 incl = tmp[t];
    offsets[t + 1] = incl;
    cursors[t] = incl - x;
    if (t == 0) offsets[0] = 0;
}

__global__ __launch_bounds__(256) void scatter_kernel(const float* __restrict__ pos,
                                                      u32* __restrict__ cursors,
                                                      u64* __restrict__ S) {
    __shared__ u32 h[1024];
    const int t = threadIdx.x;
    for (int i = t; i < 1024; i += 256) h[i] = 0;
    __syncthreads();
    const int base_n = blockIdx.x * 8192;
    for (int it = 0; it < 32; ++it) {
        const int n = base_n + (it << 8) + t;
        atomicAdd(&h[bucket_of(pos[3 * n], pos[3 * n + 1])], 1u);
    }
    __syncthreads();
    for (int i = t; i < 1024; i += 256) {
        const u32 c = h[i];
        h[i] = c ? atomicAdd(&cursors[i], c) : 0u;
    }
    __syncthreads();
    for (int it = 0; it < 32; ++it) {
        const int n = base_n + (it << 8) + t;
        const float px = pos[3 * n], py = pos[3 * n + 1], pz = pos[3 * n + 2];
        const float fxx = floorf(px), fyy = floorf(py), fzz = floorf(pz);
        const int ix = ((int)fxx) & 127, iy = ((int)fyy) & 127, iz = ((int)fzz) & 127;
        const int b = ((ix >> 2) << 5) | (iy >> 2);
        const u32 qx = (u32)((px - fxx) * 1024.0f);
        const u32 qy = (u32)((py - fyy) * 1024.0f);
        const u32 qz = (u32)((pz - fzz) * 1024.0f);
        const u64 v = (u64)iz | ((u64)(ix & 3) << 7) | ((u64)(iy & 3) << 9)
                    | ((u64)qx << 11) | ((u64)qy << 21) | ((u64)qz << 31)
                    | ((u64)(u32)n << 41);
        S[atomicAdd(&h[b], 1u)] = v;
    }
}

__device__ __forceinline__ void decode(u64 v, int& iz, int& lx, int& ly,
                                       float& fx, float& fy, float& fz, int& n) {
    iz = (int)(v & 127);
    lx = (int)((v >> 7) & 3);
    ly = (int)((v >> 9) & 3);
    const float inv = 1.0f / 1024.0f;
    fx = (float)((v >> 11) & 1023) * inv;
    fy = (float)((v >> 21) & 1023) * inv;
    fz = (float)((v >> 31) & 1023) * inv;
    n = (int)((v >> 41) & 0x1FFFFF);
}

__global__ __launch_bounds__(256) void paint_kernel(const u64* __restrict__ S,
                                                    const u32* __restrict__ offsets,
                                                    float* __restrict__ R) {
    __shared__ float tile[3200];  // 5 x 5 x 128
    const int t = threadIdx.x;
    for (int i = t; i < 3200; i += 256) tile[i] = 0.0f;
    __syncthreads();
    const int b = blockIdx.x;
    const int start = offsets[b], end = offsets[b + 1];
    for (int i = start + t; i < end; i += 256) {
        int iz, lx, ly, n;
        float fx, fy, fz;
        decode(S[i], iz, lx, ly, fx, fy, fz, n);
        const float wx[2] = {1.0f - fx, fx};
        const float wy[2] = {1.0f - fy, fy};
        const float wz[2] = {1.0f - fz, fz};
        #pragma unroll
        for (int dx = 0; dx < 2; ++dx)
            #pragma unroll
            for (int dy = 0; dy < 2; ++dy) {
                const int bi = ((lx + dx) * 5 + (ly + dy)) << 7;
                const float wxy = wx[dx] * wy[dy];
                atomicAdd(&tile[bi + iz], wxy * wz[0]);
                atomicAdd(&tile[bi + ((iz + 1) & 127)], wxy * wz[1]);
            }
    }
    __syncthreads();
    const int x0 = (b >> 5) << 2, y0 = (b & 31) << 2;
    for (int i = t; i < 3200; i += 256) {
        const int hx = i / 640;
        const int hy = (i >> 7) % 5;
        const int z = i & 127;
        const int g = (((x0 + hx) & 127) << 14) | (((y0 + hy) & 127) << 7) | z;
        atomicAdd(&R[g], tile[i]);
    }
}

__global__ __launch_bounds__(256) void readout_kernel(const u64* __restrict__ S,
                                                      const u32* __restrict__ offsets,
                                                      const float2* __restrict__ A,
                                                      const float2* __restrict__ B,
                                                      const float* __restrict__ vel,
                                                      const float* __restrict__ fdf,
                                                      float* __restrict__ out) {
    __shared__ float2 sxy[3200];
    __shared__ float  sz[3200];
    const int t = threadIdx.x;
    const int b = blockIdx.x;
    const int x0 = (b >> 5) << 2, y0 = (b & 31) << 2;
    for (int i = t; i < 3200; i += 256) {
        const int hx = i / 640;
        const int hy = (i >> 7) % 5;
        const int z = i & 127;
        const int g = (((x0 + hx) & 127) << 14) | (((y0 + hy) & 127) << 7) | z;
        sxy[i] = A[g];
        sz[i] = B[g].x;
    }
    __syncthreads();
    const float sc = 0.2f / fdf[0];
    const int start = offsets[b], end = offsets[b + 1];
    for (int i = start + t; i < end; i += 256) {
        int iz, lx, ly, n;
        float fx, fy, fz;
        decode(S[i], iz, lx, ly, fx, fy, fz, n);
        const float wx[2] = {1.0f - fx, fx};
        const float wy[2] = {1.0f - fy, fy};
        const float wz[2] = {1.0f - fz, fz};
        float gx = 0.f, gy = 0.f, gz = 0.f;
        #pragma unroll
        for (int dx = 0; dx < 2; ++dx)
            #pragma unroll
            for (int dy = 0; dy < 2; ++dy) {
                const int bi = ((lx + dx) * 5 + (ly + dy)) << 7;
                const float wxy = wx[dx] * wy[dy];
                #pragma unroll
                for (int dz = 0; dz < 2; ++dz) {
                    const int idx2 = bi + ((iz + dz) & 127);
                    const float w = wxy * wz[dz];
                    const float2 a = sxy[idx2];
                    gx += w * a.x;
                    gy += w * a.y;
                    gz += w * sz[idx2];
                }
            }
        out[3 * NPART + 3 * n + 0] = vel[3 * n + 0] + gx * sc;
        out[3 * NPART + 3 * n + 1] = vel[3 * n + 1] + gy * sc;
        out[3 * NPART + 3 * n + 2] = vel[3 * n + 2] + gz * sc;
    }
}

extern "C" void kernel_launch(void* const* d_in, const int* in_sizes, int n_in,
                              void* d_out, int out_size, void* d_ws, size_t ws_size,
                              hipStream_t stream) {
    const float* pos = (const float*)d_in[0];
    const float* vel = (const float*)d_in[1];
    const float* fdf = (const float*)d_in[2];
    float* out = (float*)d_out;

    float2* A = (float2*)d_ws;          // 16.78 MB complex grid
    float2* B = A + MESH3;              // 16.78 MB complex grid
    float*  R = (float*)B;              // real paint grid = first half of B (dead before filter)
    // d_out pos-half scratch (25.17 MB): S (16.78 MB) + counters; all consumed
    // before the final pos memcpy overwrites this region.
    u64* S       = (u64*)d_out;                           // sorted packed particles
    u32* cnt     = (u32*)((char*)d_out + (18 << 20));     // 1024
    u32* offsets = cnt + 1024;                            // 1025
    u32* cursors = offsets + 1025;                        // 1024

    hipMemsetAsync(cnt, 0, 1024 * sizeof(u32), stream);
    hist_kernel<<<256, 256, 0, stream>>>(pos, cnt);
    scan_kernel<<<1, 1024, 0, stream>>>(cnt, offsets, cursors);
    scatter_kernel<<<256, 256, 0, stream>>>(pos, cursors, S);

    hipMemsetAsync(R, 0, MESH3 * sizeof(float), stream);
    paint_kernel<<<1024, 256, 0, stream>>>(S, offsets, R);

    fft_z_fwd_real<<<1024, 256, 0, stream>>>(R, A);
    fft_pass<1, false><<<1024, 256, 0, stream>>>(A);
    fft_pass<0, false><<<1024, 256, 0, stream>>>(A);

    filter_kernel<<<MESH3 / 256, 256, 0, stream>>>(A, B);

    fft_pass<0, true><<<1024, 256, 0, stream>>>(A);
    fft_pass<1, true><<<1024, 256, 0, stream>>>(A);
    fft_pass<2, true><<<1024, 256, 0, stream>>>(A);
    fft_pass<0, true><<<1024, 256, 0, stream>>>(B);
    fft_pass<1, true><<<1024, 256, 0, stream>>>(B);
    fft_pass<2, true><<<1024, 256, 0, stream>>>(B);

    readout_kernel<<<1024, 256, 0, stream>>>(S, offsets, A, B, vel, fdf, out);
    hipMemcpyAsync(out, pos, (size_t)NPART * 3 * sizeof(float),
                   hipMemcpyDeviceToDevice, stream);
}

// Round 3
// 414.881 us; speedup vs baseline: 3.1376x; 1.0325x over previous
//
#include <hip/hip_runtime.h>

#define MESH  128
#define MESH2 16384
#define MESH3 2097152
#define NPART MESH3
#define TILE  16
typedef unsigned int u32;
typedef unsigned long long u64;

// packed particle record (8B):
//  bits [0,7)   iz
//  bits [7,9)   lx (ix & 3)
//  bits [9,11)  ly (iy & 1)  -- tiles are 4x2 columns now
//  bits [11,21) qx (frac, 10-bit)
//  bits [21,31) qy
//  bits [31,41) qz
//  bits [41,62) n  (original particle index, 21 bits)

__device__ __forceinline__ float2 cmul(float2 a, float2 b) {
    return make_float2(a.x * b.x - a.y * b.y, a.x * b.y + a.y * b.x);
}
// a * conj(b)
__device__ __forceinline__ float2 cmulc(float2 a, float2 b) {
    return make_float2(a.x * b.x + a.y * b.y, a.y * b.x - a.x * b.y);
}

template <int AXIS, bool INV>
__global__ __launch_bounds__(256) void fft_pass(float2* __restrict__ data) {
    __shared__ float2 s[MESH][TILE + 1];
    __shared__ float2 tw[64];
    const int t = threadIdx.x;
    if (t < 64) {
        float sv, cv;
        sincospif(-(float)t / 64.0f, &sv, &cv);
        tw[t] = make_float2(cv, INV ? -sv : sv);
    }

    int base = 0, estride = 1;
    if (AXIS == 2) {
        base = blockIdx.x * (TILE * MESH);
        for (int i = t; i < MESH * TILE; i += 256)
            s[i & 127][i >> 7] = data[base + i];
    } else {
        const int outer = blockIdx.x >> 3;
        const int z0 = (blockIdx.x & 7) * TILE;
        estride = (AXIS == 1) ? MESH : MESH2;
        base = (AXIS == 1) ? (outer * MESH2 + z0) : (outer * MESH + z0);
        for (int i = t; i < MESH * TILE; i += 256) {
            const int l = i & 15, e = i >> 4;
            s[e][l] = data[base + e * estride + l];
        }
    }
    __syncthreads();

    const int l  = t & 15;
    const int bb = t >> 4;
    if (!INV) {
        #pragma unroll
        for (int st = 0; st < 7; ++st) {
            const int logh = 6 - st;
            const int half = 1 << logh;
            #pragma unroll
            for (int it = 0; it < 4; ++it) {
                const int b  = bb + (it << 4);
                const int j  = b & (half - 1);
                const int g  = b >> logh;
                const int i0 = (g << (logh + 1)) + j;
                const int i1 = i0 + half;
                float2 u = s[i0][l], v = s[i1][l];
                float2 d = make_float2(u.x - v.x, u.y - v.y);
                s[i0][l] = make_float2(u.x + v.x, u.y + v.y);
                s[i1][l] = cmul(d, tw[j << st]);
            }
            __syncthreads();
        }
    } else {
        #pragma unroll
        for (int st = 0; st < 7; ++st) {
            const int half = 1 << st;
            #pragma unroll
            for (int it = 0; it < 4; ++it) {
                const int b  = bb + (it << 4);
                const int j  = b & (half - 1);
                const int g  = b >> st;
                const int i0 = (g << (st + 1)) + j;
                const int i1 = i0 + half;
                float2 u = s[i0][l];
                float2 v = cmul(s[i1][l], tw[j << (6 - st)]);
                s[i0][l] = make_float2(u.x + v.x, u.y + v.y);
                s[i1][l] = make_float2(u.x - v.x, u.y - v.y);
            }
            __syncthreads();
        }
    }

    if (AXIS == 2) {
        for (int i = t; i < MESH * TILE; i += 256)
            data[base + i] = s[i & 127][i >> 7];
    } else {
        for (int i = t; i < MESH * TILE; i += 256) {
            const int l2 = i & 15, e = i >> 4;
            data[base + e * estride + l2] = s[e][l2];
        }
    }
}

__global__ __launch_bounds__(256) void fft_z_fwd_real(const float* __restrict__ Rin,
                                                      float2* __restrict__ out) {
    __shared__ float2 s[MESH][TILE + 1];
    __shared__ float2 tw[64];
    const int t = threadIdx.x;
    if (t < 64) {
        float sv, cv;
        sincospif(-(float)t / 64.0f, &sv, &cv);
        tw[t] = make_float2(cv, sv);
    }
    const int base = blockIdx.x * (TILE * MESH);
    for (int i = t; i < MESH * TILE; i += 256)
        s[i & 127][i >> 7] = make_float2(Rin[base + i], 0.0f);
    __syncthreads();

    const int l  = t & 15;
    const int bb = t >> 4;
    #pragma unroll
    for (int st = 0; st < 7; ++st) {
        const int logh = 6 - st;
        const int half = 1 << logh;
        #pragma unroll
        for (int it = 0; it < 4; ++it) {
            const int b  = bb + (it << 4);
            const int j  = b & (half - 1);
            const int g  = b >> logh;
            const int i0 = (g << (logh + 1)) + j;
            const int i1 = i0 + half;
            float2 u = s[i0][l], v = s[i1][l];
            float2 d = make_float2(u.x - v.x, u.y - v.y);
            s[i0][l] = make_float2(u.x + v.x, u.y + v.y);
            s[i1][l] = cmul(d, tw[j << st]);
        }
        __syncthreads();
    }
    for (int i = t; i < MESH * TILE; i += 256)
        out[base + i] = s[i & 127][i >> 7];
}

// Fused: forward x-FFT (DIF) -> k-space filter -> inverse x-FFT (DIT) on both
// the (ky - i kx)*pot lines (-> A) and the -i kz*pot lines (-> B).
__global__ __launch_bounds__(256) void fft_x_mega(float2* __restrict__ A,
                                                  float2* __restrict__ B) {
    __shared__ float2 SA[MESH][TILE + 1];
    __shared__ float2 SB[MESH][TILE + 1];
    __shared__ float2 tw[64];
    const int t = threadIdx.x;
    if (t < 64) {
        float sv, cv;
        sincospif(-(float)t / 64.0f, &sv, &cv);
        tw[t] = make_float2(cv, sv);  // forward twiddle; conj applied for inverse
    }
    const int cy = blockIdx.x >> 3;          // storage y index
    const int z0 = (blockIdx.x & 7) * TILE;  // storage z tile
    const int base = cy * MESH + z0;         // element e at base + e*MESH2 + l

    for (int i = t; i < MESH * TILE; i += 256) {
        const int l = i & 15, e = i >> 4;
        SA[e][l] = A[base + e * MESH2 + l];
    }
    __syncthreads();

    const int l  = t & 15;
    const int bb = t >> 4;
    // forward DIF along x
    #pragma unroll
    for (int st = 0; st < 7; ++st) {
        const int logh = 6 - st;
        const int half = 1 << logh;
        #pragma unroll
        for (int it = 0; it < 4; ++it) {
            const int b  = bb + (it << 4);
            const int j  = b & (half - 1);
            const int g  = b >> logh;
            const int i0 = (g << (logh + 1)) + j;
            const int i1 = i0 + half;
            float2 u = SA[i0][l], v = SA[i1][l];
            float2 d = make_float2(u.x - v.x, u.y - v.y);
            SA[i0][l] = make_float2(u.x + v.x, u.y + v.y);
            SA[i1][l] = cmul(d, tw[j << st]);
        }
        __syncthreads();
    }

    // filter: element e holds freq jx = brev7(e); line has jy = brev7(cy), jz = brev7(z0+l)
    const int jy = (int)(__brev((unsigned)cy) >> 25);
    const float c = 6.28318530717958647692f / 128.0f;
    const float ky = c * (float)(jy < 64 ? jy : jy - 128);
    for (int i = t; i < MESH * TILE; i += 256) {
        const int e = i & 127, ll = i >> 7;
        const int jx = (int)(__brev((unsigned)e) >> 25);
        const int jz = (int)(__brev((unsigned)(z0 + ll)) >> 25);
        const float kx = c * (float)(jx < 64 ? jx : jx - 128);
        const float kz = c * (float)(jz < 64 ? jz : jz - 128);
        const float kk = kx * kx + ky * ky + kz * kz;
        float2 a = SA[e][ll];
        float2 av = make_float2(0.f, 0.f), bv = make_float2(0.f, 0.f);
        if (kk > 0.0f) {
            const float inv_kk = 1.0f / kk;
            const float rng = __expf(-0.09f * inv_kk - kk * kk);  // KL^2=0.09, KS^4=1
            const float sc  = -inv_kk * rng * (1.0f / 2097152.0f);
            const float pr = a.x * sc, pi = a.y * sc;
            av = make_float2(ky * pr + kx * pi, ky * pi - kx * pr);
            bv = make_float2(kz * pi, -kz * pr);
        }
        SA[e][ll] = av;
        SB[e][ll] = bv;
    }
    __syncthreads();

    // inverse DIT along x on both SA and SB
    #pragma unroll
    for (int st = 0; st < 7; ++st) {
        const int half = 1 << st;
        #pragma unroll
        for (int it = 0; it < 4; ++it) {
            const int b  = bb + (it << 4);
            const int j  = b & (half - 1);
            const int g  = b >> st;
            const int i0 = (g << (st + 1)) + j;
            const int i1 = i0 + half;
            const float2 w = tw[j << (6 - st)];
            float2 u = SA[i0][l];
            float2 v = cmulc(SA[i1][l], w);
            SA[i0][l] = make_float2(u.x + v.x, u.y + v.y);
            SA[i1][l] = make_float2(u.x - v.x, u.y - v.y);
            u = SB[i0][l];
            v = cmulc(SB[i1][l], w);
            SB[i0][l] = make_float2(u.x + v.x, u.y + v.y);
            SB[i1][l] = make_float2(u.x - v.x, u.y - v.y);
        }
        __syncthreads();
    }

    for (int i = t; i < MESH * TILE; i += 256) {
        const int l2 = i & 15, e = i >> 4;
        A[base + e * MESH2 + l2] = SA[e][l2];
        B[base + e * MESH2 + l2] = SB[e][l2];
    }
}

// ---------------- particle binning: 2048 buckets (4x2 columns) ----------------

__device__ __forceinline__ int bucket_of(float px, float py) {
    const int ix = ((int)floorf(px)) & 127;
    const int iy = ((int)floorf(py)) & 127;
    return ((ix >> 2) << 6) | (iy >> 1);
}

__global__ __launch_bounds__(256) void hist_kernel(const float* __restrict__ pos,
                                                   u32* __restrict__ cnt) {
    __shared__ u32 h[2048];
    const int t = threadIdx.x;
    for (int i = t; i < 2048; i += 256) h[i] = 0;
    __syncthreads();
    const int base_n = blockIdx.x * 8192;
    for (int it = 0; it < 32; ++it) {
        const int n = base_n + (it << 8) + t;
        atomicAdd(&h[bucket_of(pos[3 * n], pos[3 * n + 1])], 1u);
    }
    __syncthreads();
    for (int i = t; i < 2048; i += 256)
        if (h[i]) atomicAdd(&cnt[i], h[i]);
}

__global__ __launch_bounds__(1024) void scan_kernel(const u32* __restrict__ cnt,
                                                    u32* __restrict__ offsets,
                                                    u32* __restrict__ cursors) {
    __shared__ u32 tmp[1024];
    const int t = threadIdx.x;
    const u32 a = cnt[2 * t], b = cnt[2 * t + 1];
    const u32 s = a + b;
    tmp[t] = s;
    __syncthreads();
    for (int off = 1; off < 1024; off <<= 1) {
        const u32 v = (t >= off) ? tmp[t - off] : 0u;
        __syncthreads();
        tmp[t] += v;
        __syncthreads();
    }
    const u32 incl = tmp[t];
    const u32 excl = incl - s;
    offsets[2 * t + 1] = excl + a;
    offsets[2 * t + 2] = incl;
    cursors[2 * t]     = excl;
    cursors[2 * t + 1] = excl + a;
    if (t == 0) offsets[0] = 0;
}

__global__ __launch_bounds__(256) void scatter_kernel(const float* __restrict__ pos,
                                                      u32* __restrict__ cursors,
                                                      u64* __restrict__ S) {
    __shared__ u32 h[2048];
    const int t = threadIdx.x;
    for (int i = t; i < 2048; i += 256) h[i] = 0;
    __syncthreads();
    const int base_n = blockIdx.x * 8192;
    for (int it = 0; it < 32; ++it) {
        const int n = base_n + (it << 8) + t;
        atomicAdd(&h[bucket_of(pos[3 * n], pos[3 * n + 1])], 1u);
    }
    __syncthreads();
    for (int i = t; i < 2048; i += 256) {
        const u32 c = h[i];
        h[i] = c ? atomicAdd(&cursors[i], c) : 0u;
    }
    __syncthreads();
    for (int it = 0; it < 32; ++it) {
        const int n = base_n + (it << 8) + t;
        const float px = pos[3 * n], py = pos[3 * n + 1], pz = pos[3 * n + 2];
        const float fxx = floorf(px), fyy = floorf(py), fzz = floorf(pz);
        const int ix = ((int)fxx) & 127, iy = ((int)fyy) & 127, iz = ((int)fzz) & 127;
        const int b = ((ix >> 2) << 6) | (iy >> 1);
        const u32 qx = (u32)((px - fxx) * 1024.0f);
        const u32 qy = (u32)((py - fyy) * 1024.0f);
        const u32 qz = (u32)((pz - fzz) * 1024.0f);
        const u64 v = (u64)iz | ((u64)(ix & 3) << 7) | ((u64)(iy & 1) << 9)
                    | ((u64)qx << 11) | ((u64)qy << 21) | ((u64)qz << 31)
                    | ((u64)(u32)n << 41);
        S[atomicAdd(&h[b], 1u)] = v;
    }
}

__device__ __forceinline__ void decode(u64 v, int& iz, int& lx, int& ly,
                                       float& fx, float& fy, float& fz, int& n) {
    iz = (int)(v & 127);
    lx = (int)((v >> 7) & 3);
    ly = (int)((v >> 9) & 3);
    const float inv = 1.0f / 1024.0f;
    fx = (float)((v >> 11) & 1023) * inv;
    fy = (float)((v >> 21) & 1023) * inv;
    fz = (float)((v >> 31) & 1023) * inv;
    n = (int)((v >> 41) & 0x1FFFFF);
}

// tile: 5(x-halo) x 3(y-halo) x 128(z) = 1920 floats (7.68 KB LDS)
__global__ __launch_bounds__(256) void paint_kernel(const u64* __restrict__ S,
                                                    const u32* __restrict__ offsets,
                                                    float* __restrict__ R) {
    __shared__ float tile[1920];
    const int t = threadIdx.x;
    for (int i = t; i < 1920; i += 256) tile[i] = 0.0f;
    __syncthreads();
    const int b = blockIdx.x;
    const int start = offsets[b], end = offsets[b + 1];
    for (int i = start + t; i < end; i += 256) {
        int iz, lx, ly, n;
        float fx, fy, fz;
        decode(S[i], iz, lx, ly, fx, fy, fz, n);
        const float wx[2] = {1.0f - fx, fx};
        const float wy[2] = {1.0f - fy, fy};
        const float wz[2] = {1.0f - fz, fz};
        #pragma unroll
        for (int dx = 0; dx < 2; ++dx)
            #pragma unroll
            for (int dy = 0; dy < 2; ++dy) {
                const int bi = ((lx + dx) * 3 + (ly + dy)) << 7;
                const float wxy = wx[dx] * wy[dy];
                atomicAdd(&tile[bi + iz], wxy * wz[0]);
                atomicAdd(&tile[bi + ((iz + 1) & 127)], wxy * wz[1]);
            }
    }
    __syncthreads();
    const int x0 = (b >> 6) << 2, y0 = (b & 63) << 1;
    for (int i = t; i < 1920; i += 256) {
        const int hx = i / 384;
        const int hy = (i >> 7) % 3;
        const int z = i & 127;
        const int g = (((x0 + hx) & 127) << 14) | (((y0 + hy) & 127) << 7) | z;
        atomicAdd(&R[g], tile[i]);
    }
}

__global__ __launch_bounds__(256) void readout_kernel(const u64* __restrict__ S,
                                                      const u32* __restrict__ offsets,
                                                      const float2* __restrict__ A,
                                                      const float2* __restrict__ B,
                                                      const float* __restrict__ vel,
                                                      const float* __restrict__ fdf,
                                                      float* __restrict__ out) {
    __shared__ float2 sxy[1920];
    __shared__ float  sz[1920];
    const int t = threadIdx.x;
    const int b = blockIdx.x;
    const int x0 = (b >> 6) << 2, y0 = (b & 63) << 1;
    for (int i = t; i < 1920; i += 256) {
        const int hx = i / 384;
        const int hy = (i >> 7) % 3;
        const int z = i & 127;
        const int g = (((x0 + hx) & 127) << 14) | (((y0 + hy) & 127) << 7) | z;
        sxy[i] = A[g];
        sz[i] = B[g].x;
    }
    __syncthreads();
    const float sc = 0.2f / fdf[0];
    const int start = offsets[b], end = offsets[b + 1];
    for (int i = start + t; i < end; i += 256) {
        int iz, lx, ly, n;
        float fx, fy, fz;
        decode(S[i], iz, lx, ly, fx, fy, fz, n);
        const float wx[2] = {1.0f - fx, fx};
        const float wy[2] = {1.0f - fy, fy};
        const float wz[2] = {1.0f - fz, fz};
        float gx = 0.f, gy = 0.f, gz = 0.f;
        #pragma unroll
        for (int dx = 0; dx < 2; ++dx)
            #pragma unroll
            for (int dy = 0; dy < 2; ++dy) {
                const int bi = ((lx + dx) * 3 + (ly + dy)) << 7;
                const float wxy = wx[dx] * wy[dy];
                #pragma unroll
                for (int dz = 0; dz < 2; ++dz) {
                    const int idx2 = bi + ((iz + dz) & 127);
                    const float w = wxy * wz[dz];
                    const float2 a = sxy[idx2];
                    gx += w * a.x;
                    gy += w * a.y;
                    gz += w * sz[idx2];
                }
            }
        out[3 * NPART + 3 * n + 0] = vel[3 * n + 0] + gx * sc;
        out[3 * NPART + 3 * n + 1] = vel[3 * n + 1] + gy * sc;
        out[3 * NPART + 3 * n + 2] = vel[3 * n + 2] + gz * sc;
    }
}

extern "C" void kernel_launch(void* const* d_in, const int* in_sizes, int n_in,
                              void* d_out, int out_size, void* d_ws, size_t ws_size,
                              hipStream_t stream) {
    const float* pos = (const float*)d_in[0];
    const float* vel = (const float*)d_in[1];
    const float* fdf = (const float*)d_in[2];
    float* out = (float*)d_out;

    float2* A = (float2*)d_ws;          // 16.78 MB complex grid
    float2* B = A + MESH3;              // 16.78 MB complex grid
    float*  R = (float*)B;              // real paint grid (dead before fft_x_mega writes B)
    u64* S       = (u64*)d_out;                       // sorted packed particles (16.78 MB)
    u32* cnt     = (u32*)((char*)d_out + (18 << 20)); // 2048
    u32* offsets = cnt + 2048;                        // 2049
    u32* cursors = offsets + 2049;                    // 2048

    hipMemsetAsync(cnt, 0, 2048 * sizeof(u32), stream);
    hist_kernel<<<256, 256, 0, stream>>>(pos, cnt);
    scan_kernel<<<1, 1024, 0, stream>>>(cnt, offsets, cursors);
    scatter_kernel<<<256, 256, 0, stream>>>(pos, cursors, S);

    hipMemsetAsync(R, 0, MESH3 * sizeof(float), stream);
    paint_kernel<<<2048, 256, 0, stream>>>(S, offsets, R);

    fft_z_fwd_real<<<1024, 256, 0, stream>>>(R, A);
    fft_pass<1, false><<<1024, 256, 0, stream>>>(A);

    fft_x_mega<<<1024, 256, 0, stream>>>(A, B);   // fwd x + filter + inv x (A and B)

    fft_pass<1, true><<<1024, 256, 0, stream>>>(A);
    fft_pass<2, true><<<1024, 256, 0, stream>>>(A);
    fft_pass<1, true><<<1024, 256, 0, stream>>>(B);
    fft_pass<2, true><<<1024, 256, 0, stream>>>(B);

    readout_kernel<<<2048, 256, 0, stream>>>(S, offsets, A, B, vel, fdf, out);
    hipMemcpyAsync(out, pos, (size_t)NPART * 3 * sizeof(float),
                   hipMemcpyDeviceToDevice, stream);
}

// Round 4
// 399.491 us; speedup vs baseline: 3.2585x; 1.0385x over previous
//
#include <hip/hip_runtime.h>

#define MESH  128
#define MESH2 16384
#define MESH3 2097152
#define NPART MESH3
#define TILE  16
typedef unsigned int u32;
typedef unsigned short u16;
typedef unsigned long long u64;

// packed particle record (8B):
//  [0,7) iz | [7,9) lx=ix&3 | [9,10) ly=iy&1 | [11,21) qx | [21,31) qy | [31,41) qz | [41,62) n

__device__ __forceinline__ float2 cmul(float2 a, float2 b) {
    return make_float2(a.x * b.x - a.y * b.y, a.x * b.y + a.y * b.x);
}
__device__ __forceinline__ float2 cmulc(float2 a, float2 b) {  // a * conj(b)
    return make_float2(a.x * b.x + a.y * b.y, a.y * b.x - a.x * b.y);
}
__device__ __forceinline__ u16 f2bf(float x) {
    u32 b = __float_as_uint(x);
    return (u16)((b + 0x7FFFu + ((b >> 16) & 1u)) >> 16);   // RNE
}
__device__ __forceinline__ float bf2f(u16 h) {
    return __uint_as_float(((u32)h) << 16);
}

// ---------------- generic y-axis pass (used fwd on A, and dual-inverse) ------
template <bool INV>
__device__ __forceinline__ void fft_y_body(float2* __restrict__ data, int bid, int t) {
    __shared__ float2 s[MESH][TILE + 1];
    __shared__ float2 tw[64];
    if (t < 64) {
        float sv, cv;
        sincospif(-(float)t / 64.0f, &sv, &cv);
        tw[t] = make_float2(cv, INV ? -sv : sv);
    }
    const int outer = bid >> 3;
    const int z0 = (bid & 7) * TILE;
    const int base = outer * MESH2 + z0;
    for (int i = t; i < MESH * TILE; i += 256) {
        const int l = i & 15, e = i >> 4;
        s[e][l] = data[base + e * MESH + l];
    }
    __syncthreads();
    const int l  = t & 15;
    const int bb = t >> 4;
    if (!INV) {
        #pragma unroll
        for (int st = 0; st < 7; ++st) {
            const int logh = 6 - st;
            const int half = 1 << logh;
            #pragma unroll
            for (int it = 0; it < 4; ++it) {
                const int b  = bb + (it << 4);
                const int j  = b & (half - 1);
                const int g  = b >> logh;
                const int i0 = (g << (logh + 1)) + j;
                const int i1 = i0 + half;
                float2 u = s[i0][l], v = s[i1][l];
                float2 d = make_float2(u.x - v.x, u.y - v.y);
                s[i0][l] = make_float2(u.x + v.x, u.y + v.y);
                s[i1][l] = cmul(d, tw[j << st]);
            }
            __syncthreads();
        }
    } else {
        #pragma unroll
        for (int st = 0; st < 7; ++st) {
            const int half = 1 << st;
            #pragma unroll
            for (int it = 0; it < 4; ++it) {
                const int b  = bb + (it << 4);
                const int j  = b & (half - 1);
                const int g  = b >> st;
                const int i0 = (g << (st + 1)) + j;
                const int i1 = i0 + half;
                float2 u = s[i0][l];
                float2 v = cmul(s[i1][l], tw[j << (6 - st)]);
                s[i0][l] = make_float2(u.x + v.x, u.y + v.y);
                s[i1][l] = make_float2(u.x - v.x, u.y - v.y);
            }
            __syncthreads();
        }
    }
    for (int i = t; i < MESH * TILE; i += 256) {
        const int l2 = i & 15, e = i >> 4;
        data[base + e * MESH + l2] = s[e][l2];
    }
}

__global__ __launch_bounds__(256) void fft_y_fwd(float2* __restrict__ A) {
    fft_y_body<false>(A, blockIdx.x, threadIdx.x);
}
// both inverse-y passes in one dispatch: blocks [0,1024) -> A, [1024,2048) -> B
__global__ __launch_bounds__(256) void fft_y_inv_dual(float2* __restrict__ A,
                                                      float2* __restrict__ B) {
    float2* d = (blockIdx.x < 1024) ? A : B;
    fft_y_body<true>(d, blockIdx.x & 1023, threadIdx.x);
}

// ------- z-forward FFT fused with the staging-tile halo merge (paint flush) --
// ST: 2048 tiles x 1920 floats, tile layout [hx:5][hy:3][z:128].
__global__ __launch_bounds__(256) void fft_z_fwd_merge(const float* __restrict__ ST,
                                                       float2* __restrict__ out) {
    __shared__ float2 s[MESH][TILE + 1];
    __shared__ float2 tw[64];
    const int t = threadIdx.x;
    if (t < 64) {
        float sv, cv;
        sincospif(-(float)t / 64.0f, &sv, &cv);
        tw[t] = make_float2(cv, sv);
    }
    const int col0 = blockIdx.x * TILE;       // 16 (x,y) columns per block
    const int base = col0 * MESH;
    for (int i = t; i < MESH * TILE; i += 256) {
        const int lc = i >> 7;                // local column
        const int z  = i & 127;
        const int c  = col0 + lc;
        const int x = c >> 7, y = c & 127;
        const int tx = x >> 2, ty = y >> 1;
        const int hx = x & 3,  hy = y & 1;
        float v = ST[((tx << 6) | ty) * 1920 + ((hx * 3 + hy) << 7) + z];
        const int txm = (tx + 31) & 31;
        const int tym = (ty + 63) & 63;
        if (hx == 0)
            v += ST[((txm << 6) | ty) * 1920 + ((12 + hy) << 7) + z];
        if (hy == 0) {
            v += ST[((tx << 6) | tym) * 1920 + ((hx * 3 + 2) << 7) + z];
            if (hx == 0)
                v += ST[((txm << 6) | tym) * 1920 + (14 << 7) + z];
        }
        s[z][lc] = make_float2(v, 0.0f);
    }
    __syncthreads();
    const int l  = t & 15;
    const int bb = t >> 4;
    #pragma unroll
    for (int st = 0; st < 7; ++st) {
        const int logh = 6 - st;
        const int half = 1 << logh;
        #pragma unroll
        for (int it = 0; it < 4; ++it) {
            const int b  = bb + (it << 4);
            const int j  = b & (half - 1);
            const int g  = b >> logh;
            const int i0 = (g << (logh + 1)) + j;
            const int i1 = i0 + half;
            float2 u = s[i0][l], v = s[i1][l];
            float2 d = make_float2(u.x - v.x, u.y - v.y);
            s[i0][l] = make_float2(u.x + v.x, u.y + v.y);
            s[i1][l] = cmul(d, tw[j << st]);
        }
        __syncthreads();
    }
    for (int i = t; i < MESH * TILE; i += 256)
        out[base + i] = s[i & 127][i >> 7];
}

// ------- z-inverse FFT writing compact bf16 (REAL_ONLY: just Re) -------------
template <bool REAL_ONLY>
__global__ __launch_bounds__(256) void fft_z_inv_bf16(const float2* __restrict__ in,
                                                      void* __restrict__ outv) {
    __shared__ float2 s[MESH][TILE + 1];
    __shared__ float2 tw[64];
    const int t = threadIdx.x;
    if (t < 64) {
        float sv, cv;
        sincospif(-(float)t / 64.0f, &sv, &cv);
        tw[t] = make_float2(cv, -sv);
    }
    const int base = blockIdx.x * (TILE * MESH);
    for (int i = t; i < MESH * TILE; i += 256)
        s[i & 127][i >> 7] = in[base + i];
    __syncthreads();
    const int l  = t & 15;
    const int bb = t >> 4;
    #pragma unroll
    for (int st = 0; st < 7; ++st) {
        const int half = 1 << st;
        #pragma unroll
        for (int it = 0; it < 4; ++it) {
            const int b  = bb + (it << 4);
            const int j  = b & (half - 1);
            const int g  = b >> st;
            const int i0 = (g << (st + 1)) + j;
            const int i1 = i0 + half;
            float2 u = s[i0][l];
            float2 v = cmul(s[i1][l], tw[j << (6 - st)]);
            s[i0][l] = make_float2(u.x + v.x, u.y + v.y);
            s[i1][l] = make_float2(u.x - v.x, u.y - v.y);
        }
        __syncthreads();
    }
    if (REAL_ONLY) {
        u16* outr = (u16*)outv;
        for (int i = t; i < MESH * TILE; i += 256)
            outr[base + i] = f2bf(s[i & 127][i >> 7].x);
    } else {
        u32* outc = (u32*)outv;
        for (int i = t; i < MESH * TILE; i += 256) {
            const float2 v = s[i & 127][i >> 7];
            outc[base + i] = (u32)f2bf(v.x) | ((u32)f2bf(v.y) << 16);
        }
    }
}

// Fused: forward x-FFT (DIF) -> filter -> inverse x-FFT (DIT) on A and B lines.
__global__ __launch_bounds__(256) void fft_x_mega(float2* __restrict__ A,
                                                  float2* __restrict__ B) {
    __shared__ float2 SA[MESH][TILE + 1];
    __shared__ float2 SB[MESH][TILE + 1];
    __shared__ float2 tw[64];
    const int t = threadIdx.x;
    if (t < 64) {
        float sv, cv;
        sincospif(-(float)t / 64.0f, &sv, &cv);
        tw[t] = make_float2(cv, sv);
    }
    const int cy = blockIdx.x >> 3;
    const int z0 = (blockIdx.x & 7) * TILE;
    const int base = cy * MESH + z0;

    for (int i = t; i < MESH * TILE; i += 256) {
        const int l = i & 15, e = i >> 4;
        SA[e][l] = A[base + e * MESH2 + l];
    }
    __syncthreads();

    const int l  = t & 15;
    const int bb = t >> 4;
    #pragma unroll
    for (int st = 0; st < 7; ++st) {
        const int logh = 6 - st;
        const int half = 1 << logh;
        #pragma unroll
        for (int it = 0; it < 4; ++it) {
            const int b  = bb + (it << 4);
            const int j  = b & (half - 1);
            const int g  = b >> logh;
            const int i0 = (g << (logh + 1)) + j;
            const int i1 = i0 + half;
            float2 u = SA[i0][l], v = SA[i1][l];
            float2 d = make_float2(u.x - v.x, u.y - v.y);
            SA[i0][l] = make_float2(u.x + v.x, u.y + v.y);
            SA[i1][l] = cmul(d, tw[j << st]);
        }
        __syncthreads();
    }

    const int jy = (int)(__brev((unsigned)cy) >> 25);
    const float c = 6.28318530717958647692f / 128.0f;
    const float ky = c * (float)(jy < 64 ? jy : jy - 128);
    for (int i = t; i < MESH * TILE; i += 256) {
        const int e = i & 127, ll = i >> 7;
        const int jx = (int)(__brev((unsigned)e) >> 25);
        const int jz = (int)(__brev((unsigned)(z0 + ll)) >> 25);
        const float kx = c * (float)(jx < 64 ? jx : jx - 128);
        const float kz = c * (float)(jz < 64 ? jz : jz - 128);
        const float kk = kx * kx + ky * ky + kz * kz;
        float2 a = SA[e][ll];
        float2 av = make_float2(0.f, 0.f), bv = make_float2(0.f, 0.f);
        if (kk > 0.0f) {
            const float inv_kk = 1.0f / kk;
            const float rng = __expf(-0.09f * inv_kk - kk * kk);  // KL^2=0.09, KS^4=1
            const float sc  = -inv_kk * rng * (1.0f / 2097152.0f);
            const float pr = a.x * sc, pi = a.y * sc;
            av = make_float2(ky * pr + kx * pi, ky * pi - kx * pr);
            bv = make_float2(kz * pi, -kz * pr);
        }
        SA[e][ll] = av;
        SB[e][ll] = bv;
    }
    __syncthreads();

    #pragma unroll
    for (int st = 0; st < 7; ++st) {
        const int half = 1 << st;
        #pragma unroll
        for (int it = 0; it < 4; ++it) {
            const int b  = bb + (it << 4);
            const int j  = b & (half - 1);
            const int g  = b >> st;
            const int i0 = (g << (st + 1)) + j;
            const int i1 = i0 + half;
            const float2 w = tw[j << (6 - st)];
            float2 u = SA[i0][l];
            float2 v = cmulc(SA[i1][l], w);
            SA[i0][l] = make_float2(u.x + v.x, u.y + v.y);
            SA[i1][l] = make_float2(u.x - v.x, u.y - v.y);
            u = SB[i0][l];
            v = cmulc(SB[i1][l], w);
            SB[i0][l] = make_float2(u.x + v.x, u.y + v.y);
            SB[i1][l] = make_float2(u.x - v.x, u.y - v.y);
        }
        __syncthreads();
    }

    for (int i = t; i < MESH * TILE; i += 256) {
        const int l2 = i & 15, e = i >> 4;
        A[base + e * MESH2 + l2] = SA[e][l2];
        B[base + e * MESH2 + l2] = SB[e][l2];
    }
}

// ---------------- particle binning: 2048 buckets (4x2 columns) ----------------

__device__ __forceinline__ int bucket_of(float px, float py) {
    const int ix = ((int)floorf(px)) & 127;
    const int iy = ((int)floorf(py)) & 127;
    return ((ix >> 2) << 6) | (iy >> 1);
}

__global__ __launch_bounds__(256) void hist_kernel(const float* __restrict__ pos,
                                                   u32* __restrict__ cnt) {
    __shared__ u32 h[2048];
    const int t = threadIdx.x;
    for (int i = t; i < 2048; i += 256) h[i] = 0;
    __syncthreads();
    const int base_n = blockIdx.x * 8192;
    for (int it = 0; it < 32; ++it) {
        const int n = base_n + (it << 8) + t;
        atomicAdd(&h[bucket_of(pos[3 * n], pos[3 * n + 1])], 1u);
    }
    __syncthreads();
    for (int i = t; i < 2048; i += 256)
        if (h[i]) atomicAdd(&cnt[i], h[i]);
}

__global__ __launch_bounds__(1024) void scan_kernel(const u32* __restrict__ cnt,
                                                    u32* __restrict__ offsets,
                                                    u32* __restrict__ cursors) {
    __shared__ u32 tmp[1024];
    const int t = threadIdx.x;
    const u32 a = cnt[2 * t], b = cnt[2 * t + 1];
    const u32 s = a + b;
    tmp[t] = s;
    __syncthreads();
    for (int off = 1; off < 1024; off <<= 1) {
        const u32 v = (t >= off) ? tmp[t - off] : 0u;
        __syncthreads();
        tmp[t] += v;
        __syncthreads();
    }
    const u32 incl = tmp[t];
    const u32 excl = incl - s;
    offsets[2 * t + 1] = excl + a;
    offsets[2 * t + 2] = incl;
    cursors[2 * t]     = excl;
    cursors[2 * t + 1] = excl + a;
    if (t == 0) offsets[0] = 0;
}

__global__ __launch_bounds__(256) void scatter_kernel(const float* __restrict__ pos,
                                                      u32* __restrict__ cursors,
                                                      u64* __restrict__ S) {
    __shared__ u32 h[2048];
    const int t = threadIdx.x;
    for (int i = t; i < 2048; i += 256) h[i] = 0;
    __syncthreads();
    const int base_n = blockIdx.x * 8192;
    for (int it = 0; it < 32; ++it) {
        const int n = base_n + (it << 8) + t;
        atomicAdd(&h[bucket_of(pos[3 * n], pos[3 * n + 1])], 1u);
    }
    __syncthreads();
    for (int i = t; i < 2048; i += 256) {
        const u32 c = h[i];
        h[i] = c ? atomicAdd(&cursors[i], c) : 0u;
    }
    __syncthreads();
    for (int it = 0; it < 32; ++it) {
        const int n = base_n + (it << 8) + t;
        const float px = pos[3 * n], py = pos[3 * n + 1], pz = pos[3 * n + 2];
        const float fxx = floorf(px), fyy = floorf(py), fzz = floorf(pz);
        const int ix = ((int)fxx) & 127, iy = ((int)fyy) & 127, iz = ((int)fzz) & 127;
        const int b = ((ix >> 2) << 6) | (iy >> 1);
        const u32 qx = (u32)((px - fxx) * 1024.0f);
        const u32 qy = (u32)((py - fyy) * 1024.0f);
        const u32 qz = (u32)((pz - fzz) * 1024.0f);
        const u64 v = (u64)iz | ((u64)(ix & 3) << 7) | ((u64)(iy & 1) << 9)
                    | ((u64)qx << 11) | ((u64)qy << 21) | ((u64)qz << 31)
                    | ((u64)(u32)n << 41);
        S[atomicAdd(&h[b], 1u)] = v;
    }
}

__device__ __forceinline__ void decode(u64 v, int& iz, int& lx, int& ly,
                                       float& fx, float& fy, float& fz, int& n) {
    iz = (int)(v & 127);
    lx = (int)((v >> 7) & 3);
    ly = (int)((v >> 9) & 3);
    const float inv = 1.0f / 1024.0f;
    fx = (float)((v >> 11) & 1023) * inv;
    fy = (float)((v >> 21) & 1023) * inv;
    fz = (float)((v >> 31) & 1023) * inv;
    n = (int)((v >> 41) & 0x1FFFFF);
}

// paint into LDS tile, flush NON-ATOMICALLY to private staging slot.
__global__ __launch_bounds__(256) void paint_kernel(const u64* __restrict__ S,
                                                    const u32* __restrict__ offsets,
                                                    float* __restrict__ ST) {
    __shared__ float tile[1920];  // 5 x 3 x 128
    const int t = threadIdx.x;
    for (int i = t; i < 1920; i += 256) tile[i] = 0.0f;
    __syncthreads();
    const int b = blockIdx.x;
    const int start = offsets[b], end = offsets[b + 1];
    for (int i = start + t; i < end; i += 256) {
        int iz, lx, ly, n;
        float fx, fy, fz;
        decode(S[i], iz, lx, ly, fx, fy, fz, n);
        const float wx[2] = {1.0f - fx, fx};
        const float wy[2] = {1.0f - fy, fy};
        const float wz[2] = {1.0f - fz, fz};
        #pragma unroll
        for (int dx = 0; dx < 2; ++dx)
            #pragma unroll
            for (int dy = 0; dy < 2; ++dy) {
                const int bi = ((lx + dx) * 3 + (ly + dy)) << 7;
                const float wxy = wx[dx] * wy[dy];
                atomicAdd(&tile[bi + iz], wxy * wz[0]);
                atomicAdd(&tile[bi + ((iz + 1) & 127)], wxy * wz[1]);
            }
    }
    __syncthreads();
    float* dst = ST + b * 1920;
    for (int i = t; i < 1920; i += 256) dst[i] = tile[i];
}

__global__ __launch_bounds__(256) void readout_kernel(const u64* __restrict__ S,
                                                      const u32* __restrict__ offsets,
                                                      const u32* __restrict__ Abf,
                                                      const u16* __restrict__ Brl,
                                                      const float* __restrict__ vel,
                                                      const float* __restrict__ fdf,
                                                      float* __restrict__ out) {
    __shared__ float2 sxy[1920];
    __shared__ float  szz[1920];
    const int t = threadIdx.x;
    const int b = blockIdx.x;
    const int x0 = (b >> 6) << 2, y0 = (b & 63) << 1;
    for (int i = t; i < 1920; i += 256) {
        const int hx = i / 384;
        const int hy = (i >> 7) % 3;
        const int z = i & 127;
        const int g = (((x0 + hx) & 127) << 14) | (((y0 + hy) & 127) << 7) | z;
        const u32 ab = Abf[g];
        sxy[i] = make_float2(__uint_as_float(ab << 16),
                             __uint_as_float(ab & 0xFFFF0000u));
        szz[i] = bf2f(Brl[g]);
    }
    __syncthreads();
    const float sc = 0.2f / fdf[0];
    const int start = offsets[b], end = offsets[b + 1];
    for (int i = start + t; i < end; i += 256) {
        int iz, lx, ly, n;
        float fx, fy, fz;
        decode(S[i], iz, lx, ly, fx, fy, fz, n);
        const float wx[2] = {1.0f - fx, fx};
        const float wy[2] = {1.0f - fy, fy};
        const float wz[2] = {1.0f - fz, fz};
        float gx = 0.f, gy = 0.f, gz = 0.f;
        #pragma unroll
        for (int dx = 0; dx < 2; ++dx)
            #pragma unroll
            for (int dy = 0; dy < 2; ++dy) {
                const int bi = ((lx + dx) * 3 + (ly + dy)) << 7;
                const float wxy = wx[dx] * wy[dy];
                #pragma unroll
                for (int dz = 0; dz < 2; ++dz) {
                    const int idx2 = bi + ((iz + dz) & 127);
                    const float w = wxy * wz[dz];
                    const float2 a = sxy[idx2];
                    gx += w * a.x;
                    gy += w * a.y;
                    gz += w * szz[idx2];
                }
            }
        out[3 * NPART + 3 * n + 0] = vel[3 * n + 0] + gx * sc;
        out[3 * NPART + 3 * n + 1] = vel[3 * n + 1] + gy * sc;
        out[3 * NPART + 3 * n + 2] = vel[3 * n + 2] + gz * sc;
    }
}

extern "C" void kernel_launch(void* const* d_in, const int* in_sizes, int n_in,
                              void* d_out, int out_size, void* d_ws, size_t ws_size,
                              hipStream_t stream) {
    const float* pos = (const float*)d_in[0];
    const float* vel = (const float*)d_in[1];
    const float* fdf = (const float*)d_in[2];
    float* out = (float*)d_out;

    float2* A  = (float2*)d_ws;            // 16.78 MB complex grid
    float2* B  = A + MESH3;                // 16.78 MB complex grid
    float*  ST = (float*)B;                // 15.7 MB paint staging (dead before mega writes B)
    u32*    Abf = (u32*)B;                 // 8.39 MB bf16x2 A-field (B dead by then)
    // d_out pos-half scratch (all dead before the final pos memcpy):
    u64* S    = (u64*)d_out;                            // 16.78 MB sorted particles
    u16* Brl  = (u16*)((char*)d_out + (MESH3 * 8));     // 4.19 MB bf16 fz field
    u32* cnt     = (u32*)((char*)d_out + (21 << 20));   // 2048
    u32* offsets = cnt + 2048;                          // 2049
    u32* cursors = offsets + 2049;                      // 2048

    hipMemsetAsync(cnt, 0, 2048 * sizeof(u32), stream);
    hist_kernel<<<256, 256, 0, stream>>>(pos, cnt);
    scan_kernel<<<1, 1024, 0, stream>>>(cnt, offsets, cursors);
    scatter_kernel<<<256, 256, 0, stream>>>(pos, cursors, S);

    paint_kernel<<<2048, 256, 0, stream>>>(S, offsets, ST);

    fft_z_fwd_merge<<<1024, 256, 0, stream>>>(ST, A);   // halo merge + fwd z
    fft_y_fwd<<<1024, 256, 0, stream>>>(A);
    fft_x_mega<<<1024, 256, 0, stream>>>(A, B);         // fwd x + filter + inv x (A,B)
    fft_y_inv_dual<<<2048, 256, 0, stream>>>(A, B);     // inv y on both grids
    fft_z_inv_bf16<true><<<1024, 256, 0, stream>>>(B, (void*)Brl);   // B -> bf16 Re
    fft_z_inv_bf16<false><<<1024, 256, 0, stream>>>(A, (void*)Abf);  // A -> bf16x2

    readout_kernel<<<2048, 256, 0, stream>>>(S, offsets, Abf, Brl, vel, fdf, out);
    hipMemcpyAsync(out, pos, (size_t)NPART * 3 * sizeof(float),
                   hipMemcpyDeviceToDevice, stream);
}

// Round 5
// 345.364 us; speedup vs baseline: 3.7692x; 1.1567x over previous
//
#include <hip/hip_runtime.h>

#define MESH  128
#define MESH2 16384
#define MESH3 2097152
#define NPART MESH3
#define TILE  16
#define CAP   6
typedef unsigned int u32;
typedef unsigned short u16;
typedef unsigned long long u64;

// packed particle record (8B):
//  [0,7) iz | [7,9) lx=ix&3 | [9,10) ly=iy&1 | [11,21) qx | [21,31) qy | [31,41) qz | [41,62) n

__device__ __forceinline__ float2 cmul(float2 a, float2 b) {
    return make_float2(a.x * b.x - a.y * b.y, a.x * b.y + a.y * b.x);
}
__device__ __forceinline__ float2 cmulc(float2 a, float2 b) {  // a * conj(b)
    return make_float2(a.x * b.x + a.y * b.y, a.y * b.x - a.x * b.y);
}
__device__ __forceinline__ u16 f2bf(float x) {
    u32 b = __float_as_uint(x);
    return (u16)((b + 0x7FFFu + ((b >> 16) & 1u)) >> 16);   // RNE
}
__device__ __forceinline__ float bf2f(u16 h) {
    return __uint_as_float(((u32)h) << 16);
}

// ---------------- generic y-axis pass (used fwd on A, and dual-inverse) ------
template <bool INV>
__device__ __forceinline__ void fft_y_body(float2* __restrict__ data, int bid, int t) {
    __shared__ float2 s[MESH][TILE + 1];
    __shared__ float2 tw[64];
    if (t < 64) {
        float sv, cv;
        sincospif(-(float)t / 64.0f, &sv, &cv);
        tw[t] = make_float2(cv, INV ? -sv : sv);
    }
    const int outer = bid >> 3;
    const int z0 = (bid & 7) * TILE;
    const int base = outer * MESH2 + z0;
    for (int i = t; i < MESH * TILE; i += 256) {
        const int l = i & 15, e = i >> 4;
        s[e][l] = data[base + e * MESH + l];
    }
    __syncthreads();
    const int l  = t & 15;
    const int bb = t >> 4;
    if (!INV) {
        #pragma unroll
        for (int st = 0; st < 7; ++st) {
            const int logh = 6 - st;
            const int half = 1 << logh;
            #pragma unroll
            for (int it = 0; it < 4; ++it) {
                const int b  = bb + (it << 4);
                const int j  = b & (half - 1);
                const int g  = b >> logh;
                const int i0 = (g << (logh + 1)) + j;
                const int i1 = i0 + half;
                float2 u = s[i0][l], v = s[i1][l];
                float2 d = make_float2(u.x - v.x, u.y - v.y);
                s[i0][l] = make_float2(u.x + v.x, u.y + v.y);
                s[i1][l] = cmul(d, tw[j << st]);
            }
            __syncthreads();
        }
    } else {
        #pragma unroll
        for (int st = 0; st < 7; ++st) {
            const int half = 1 << st;
            #pragma unroll
            for (int it = 0; it < 4; ++it) {
                const int b  = bb + (it << 4);
                const int j  = b & (half - 1);
                const int g  = b >> st;
                const int i0 = (g << (st + 1)) + j;
                const int i1 = i0 + half;
                float2 u = s[i0][l];
                float2 v = cmul(s[i1][l], tw[j << (6 - st)]);
                s[i0][l] = make_float2(u.x + v.x, u.y + v.y);
                s[i1][l] = make_float2(u.x - v.x, u.y - v.y);
            }
            __syncthreads();
        }
    }
    for (int i = t; i < MESH * TILE; i += 256) {
        const int l2 = i & 15, e = i >> 4;
        data[base + e * MESH + l2] = s[e][l2];
    }
}

__global__ __launch_bounds__(256) void fft_y_fwd(float2* __restrict__ A) {
    fft_y_body<false>(A, blockIdx.x, threadIdx.x);
}
__global__ __launch_bounds__(256) void fft_y_inv_dual(float2* __restrict__ A,
                                                      float2* __restrict__ B) {
    float2* d = (blockIdx.x < 1024) ? A : B;
    fft_y_body<true>(d, blockIdx.x & 1023, threadIdx.x);
}

// ------- z-forward FFT fused with the staging-tile halo merge (paint flush) --
// ST: 2048 tiles x 1920 floats, tile layout [hx:5][hy:3][z:128].
__global__ __launch_bounds__(256) void fft_z_fwd_merge(const float* __restrict__ ST,
                                                       float2* __restrict__ out) {
    __shared__ float2 s[MESH][TILE + 1];
    __shared__ float2 tw[64];
    const int t = threadIdx.x;
    if (t < 64) {
        float sv, cv;
        sincospif(-(float)t / 64.0f, &sv, &cv);
        tw[t] = make_float2(cv, sv);
    }
    const int col0 = blockIdx.x * TILE;
    const int base = col0 * MESH;
    for (int i = t; i < MESH * TILE; i += 256) {
        const int lc = i >> 7;
        const int z  = i & 127;
        const int c  = col0 + lc;
        const int x = c >> 7, y = c & 127;
        const int tx = x >> 2, ty = y >> 1;
        const int hx = x & 3,  hy = y & 1;
        float v = ST[((tx << 6) | ty) * 1920 + ((hx * 3 + hy) << 7) + z];
        const int txm = (tx + 31) & 31;
        const int tym = (ty + 63) & 63;
        if (hx == 0)
            v += ST[((txm << 6) | ty) * 1920 + ((12 + hy) << 7) + z];
        if (hy == 0) {
            v += ST[((tx << 6) | tym) * 1920 + ((hx * 3 + 2) << 7) + z];
            if (hx == 0)
                v += ST[((txm << 6) | tym) * 1920 + (14 << 7) + z];
        }
        s[z][lc] = make_float2(v, 0.0f);
    }
    __syncthreads();
    const int l  = t & 15;
    const int bb = t >> 4;
    #pragma unroll
    for (int st = 0; st < 7; ++st) {
        const int logh = 6 - st;
        const int half = 1 << logh;
        #pragma unroll
        for (int it = 0; it < 4; ++it) {
            const int b  = bb + (it << 4);
            const int j  = b & (half - 1);
            const int g  = b >> logh;
            const int i0 = (g << (logh + 1)) + j;
            const int i1 = i0 + half;
            float2 u = s[i0][l], v = s[i1][l];
            float2 d = make_float2(u.x - v.x, u.y - v.y);
            s[i0][l] = make_float2(u.x + v.x, u.y + v.y);
            s[i1][l] = cmul(d, tw[j << st]);
        }
        __syncthreads();
    }
    for (int i = t; i < MESH * TILE; i += 256)
        out[base + i] = s[i & 127][i >> 7];
}

// ------- z-inverse FFT writing compact bf16 (REAL_ONLY: just Re) -------------
template <bool REAL_ONLY>
__global__ __launch_bounds__(256) void fft_z_inv_bf16(const float2* __restrict__ in,
                                                      void* __restrict__ outv) {
    __shared__ float2 s[MESH][TILE + 1];
    __shared__ float2 tw[64];
    const int t = threadIdx.x;
    if (t < 64) {
        float sv, cv;
        sincospif(-(float)t / 64.0f, &sv, &cv);
        tw[t] = make_float2(cv, -sv);
    }
    const int base = blockIdx.x * (TILE * MESH);
    for (int i = t; i < MESH * TILE; i += 256)
        s[i & 127][i >> 7] = in[base + i];
    __syncthreads();
    const int l  = t & 15;
    const int bb = t >> 4;
    #pragma unroll
    for (int st = 0; st < 7; ++st) {
        const int half = 1 << st;
        #pragma unroll
        for (int it = 0; it < 4; ++it) {
            const int b  = bb + (it << 4);
            const int j  = b & (half - 1);
            const int g  = b >> st;
            const int i0 = (g << (st + 1)) + j;
            const int i1 = i0 + half;
            float2 u = s[i0][l];
            float2 v = cmul(s[i1][l], tw[j << (6 - st)]);
            s[i0][l] = make_float2(u.x + v.x, u.y + v.y);
            s[i1][l] = make_float2(u.x - v.x, u.y - v.y);
        }
        __syncthreads();
    }
    if (REAL_ONLY) {
        u16* outr = (u16*)outv;
        for (int i = t; i < MESH * TILE; i += 256)
            outr[base + i] = f2bf(s[i & 127][i >> 7].x);
    } else {
        u32* outc = (u32*)outv;
        for (int i = t; i < MESH * TILE; i += 256) {
            const float2 v = s[i & 127][i >> 7];
            outc[base + i] = (u32)f2bf(v.x) | ((u32)f2bf(v.y) << 16);
        }
    }
}

// Fused: forward x-FFT (DIF) -> filter -> inverse x-FFT (DIT) on A and B lines.
__global__ __launch_bounds__(256) void fft_x_mega(float2* __restrict__ A,
                                                  float2* __restrict__ B) {
    __shared__ float2 SA[MESH][TILE + 1];
    __shared__ float2 SB[MESH][TILE + 1];
    __shared__ float2 tw[64];
    const int t = threadIdx.x;
    if (t < 64) {
        float sv, cv;
        sincospif(-(float)t / 64.0f, &sv, &cv);
        tw[t] = make_float2(cv, sv);
    }
    const int cy = blockIdx.x >> 3;
    const int z0 = (blockIdx.x & 7) * TILE;
    const int base = cy * MESH + z0;

    for (int i = t; i < MESH * TILE; i += 256) {
        const int l = i & 15, e = i >> 4;
        SA[e][l] = A[base + e * MESH2 + l];
    }
    __syncthreads();

    const int l  = t & 15;
    const int bb = t >> 4;
    #pragma unroll
    for (int st = 0; st < 7; ++st) {
        const int logh = 6 - st;
        const int half = 1 << logh;
        #pragma unroll
        for (int it = 0; it < 4; ++it) {
            const int b  = bb + (it << 4);
            const int j  = b & (half - 1);
            const int g  = b >> logh;
            const int i0 = (g << (logh + 1)) + j;
            const int i1 = i0 + half;
            float2 u = SA[i0][l], v = SA[i1][l];
            float2 d = make_float2(u.x - v.x, u.y - v.y);
            SA[i0][l] = make_float2(u.x + v.x, u.y + v.y);
            SA[i1][l] = cmul(d, tw[j << st]);
        }
        __syncthreads();
    }

    const int jy = (int)(__brev((unsigned)cy) >> 25);
    const float c = 6.28318530717958647692f / 128.0f;
    const float ky = c * (float)(jy < 64 ? jy : jy - 128);
    for (int i = t; i < MESH * TILE; i += 256) {
        const int e = i & 127, ll = i >> 7;
        const int jx = (int)(__brev((unsigned)e) >> 25);
        const int jz = (int)(__brev((unsigned)(z0 + ll)) >> 25);
        const float kx = c * (float)(jx < 64 ? jx : jx - 128);
        const float kz = c * (float)(jz < 64 ? jz : jz - 128);
        const float kk = kx * kx + ky * ky + kz * kz;
        float2 a = SA[e][ll];
        float2 av = make_float2(0.f, 0.f), bv = make_float2(0.f, 0.f);
        if (kk > 0.0f) {
            const float inv_kk = 1.0f / kk;
            const float rng = __expf(-0.09f * inv_kk - kk * kk);  // KL^2=0.09, KS^4=1
            const float sc  = -inv_kk * rng * (1.0f / 2097152.0f);
            const float pr = a.x * sc, pi = a.y * sc;
            av = make_float2(ky * pr + kx * pi, ky * pi - kx * pr);
            bv = make_float2(kz * pi, -kz * pr);
        }
        SA[e][ll] = av;
        SB[e][ll] = bv;
    }
    __syncthreads();

    #pragma unroll
    for (int st = 0; st < 7; ++st) {
        const int half = 1 << st;
        #pragma unroll
        for (int it = 0; it < 4; ++it) {
            const int b  = bb + (it << 4);
            const int j  = b & (half - 1);
            const int g  = b >> st;
            const int i0 = (g << (st + 1)) + j;
            const int i1 = i0 + half;
            const float2 w = tw[j << (6 - st)];
            float2 u = SA[i0][l];
            float2 v = cmulc(SA[i1][l], w);
            SA[i0][l] = make_float2(u.x + v.x, u.y + v.y);
            SA[i1][l] = make_float2(u.x - v.x, u.y - v.y);
            u = SB[i0][l];
            v = cmulc(SB[i1][l], w);
            SB[i0][l] = make_float2(u.x + v.x, u.y + v.y);
            SB[i1][l] = make_float2(u.x - v.x, u.y - v.y);
        }
        __syncthreads();
    }

    for (int i = t; i < MESH * TILE; i += 256) {
        const int l2 = i & 15, e = i >> 4;
        A[base + e * MESH2 + l2] = SA[e][l2];
        B[base + e * MESH2 + l2] = SB[e][l2];
    }
}

// ---------------- particle binning: 2048 buckets (4x2 columns) ----------------

__device__ __forceinline__ int bucket_of(float px, float py) {
    const int ix = ((int)floorf(px)) & 127;
    const int iy = ((int)floorf(py)) & 127;
    return ((ix >> 2) << 6) | (iy >> 1);
}

__global__ __launch_bounds__(256) void hist_kernel(const float* __restrict__ pos,
                                                   u32* __restrict__ cnt) {
    __shared__ u32 h[2048];
    const int t = threadIdx.x;
    for (int i = t; i < 2048; i += 256) h[i] = 0;
    __syncthreads();
    const int base_n = blockIdx.x * 8192;
    for (int it = 0; it < 32; ++it) {
        const int n = base_n + (it << 8) + t;
        atomicAdd(&h[bucket_of(pos[3 * n], pos[3 * n + 1])], 1u);
    }
    __syncthreads();
    for (int i = t; i < 2048; i += 256)
        if (h[i]) atomicAdd(&cnt[i], h[i]);
}

__global__ __launch_bounds__(1024) void scan_kernel(const u32* __restrict__ cnt,
                                                    u32* __restrict__ offsets,
                                                    u32* __restrict__ cursors) {
    __shared__ u32 tmp[1024];
    const int t = threadIdx.x;
    const u32 a = cnt[2 * t], b = cnt[2 * t + 1];
    const u32 s = a + b;
    tmp[t] = s;
    __syncthreads();
    for (int off = 1; off < 1024; off <<= 1) {
        const u32 v = (t >= off) ? tmp[t - off] : 0u;
        __syncthreads();
        tmp[t] += v;
        __syncthreads();
    }
    const u32 incl = tmp[t];
    const u32 excl = incl - s;
    offsets[2 * t + 1] = excl + a;
    offsets[2 * t + 2] = incl;
    cursors[2 * t]     = excl;
    cursors[2 * t + 1] = excl + a;
    if (t == 0) offsets[0] = 0;
}

__global__ __launch_bounds__(256) void scatter_kernel(const float* __restrict__ pos,
                                                      u32* __restrict__ cursors,
                                                      u64* __restrict__ S) {
    __shared__ u32 h[2048];
    const int t = threadIdx.x;
    for (int i = t; i < 2048; i += 256) h[i] = 0;
    __syncthreads();
    const int base_n = blockIdx.x * 8192;
    for (int it = 0; it < 32; ++it) {
        const int n = base_n + (it << 8) + t;
        atomicAdd(&h[bucket_of(pos[3 * n], pos[3 * n + 1])], 1u);
    }
    __syncthreads();
    for (int i = t; i < 2048; i += 256) {
        const u32 c = h[i];
        h[i] = c ? atomicAdd(&cursors[i], c) : 0u;
    }
    __syncthreads();
    for (int it = 0; it < 32; ++it) {
        const int n = base_n + (it << 8) + t;
        const float px = pos[3 * n], py = pos[3 * n + 1], pz = pos[3 * n + 2];
        const float fxx = floorf(px), fyy = floorf(py), fzz = floorf(pz);
        const int ix = ((int)fxx) & 127, iy = ((int)fyy) & 127, iz = ((int)fzz) & 127;
        const int b = ((ix >> 2) << 6) | (iy >> 1);
        const u32 qx = (u32)((px - fxx) * 1024.0f);
        const u32 qy = (u32)((py - fyy) * 1024.0f);
        const u32 qz = (u32)((pz - fzz) * 1024.0f);
        const u64 v = (u64)iz | ((u64)(ix & 3) << 7) | ((u64)(iy & 1) << 9)
                    | ((u64)qx << 11) | ((u64)qy << 21) | ((u64)qz << 31)
                    | ((u64)(u32)n << 41);
        S[atomicAdd(&h[b], 1u)] = v;
    }
}

__device__ __forceinline__ void decode(u64 v, int& iz, int& lx, int& ly,
                                       float& fx, float& fy, float& fz, int& n) {
    iz = (int)(v & 127);
    lx = (int)((v >> 7) & 3);
    ly = (int)((v >> 9) & 3);
    const float inv = 1.0f / 1024.0f;
    fx = (float)((v >> 11) & 1023) * inv;
    fy = (float)((v >> 21) & 1023) * inv;
    fz = (float)((v >> 31) & 1023) * inv;
    n = (int)((v >> 41) & 0x1FFFFF);
}

// GATHER-based paint: bin particles by local cell (1 LDS atomic each), then
// each staging cell gathers from <=8 neighbor cell lists (LDS reads, no atomics).
__global__ __launch_bounds__(256) void paint_kernel(const u64* __restrict__ S,
                                                    const u32* __restrict__ offsets,
                                                    float* __restrict__ ST) {
    __shared__ u32 cnt[1024];        // per local cell (bx[0..3], by[0..1], bz[0..127])
    __shared__ u32 rec[1024 * CAP];  // qx|qy<<10|qz<<20
    __shared__ u64 ovf[128];
    __shared__ u32 novf;
    const int t = threadIdx.x;
    for (int i = t; i < 1024; i += 256) cnt[i] = 0;
    if (t == 0) novf = 0;
    __syncthreads();
    const int b = blockIdx.x;
    const int start = offsets[b], end = offsets[b + 1];
    for (int i = start + t; i < end; i += 256) {
        const u64 v = S[i];
        const int iz = (int)(v & 127);
        const int lx = (int)((v >> 7) & 3);
        const int ly = (int)((v >> 9) & 1);
        const int cell = (((lx << 1) | ly) << 7) | iz;
        const u32 r = (u32)((v >> 11) & 0x3FFFFFFFull);
        const u32 slot = atomicAdd(&cnt[cell], 1u);
        if (slot < CAP) rec[cell * CAP + slot] = r;
        else {
            const u32 o = atomicAdd(&novf, 1u);
            if (o < 128u) ovf[o] = ((u64)cell << 32) | r;
        }
    }
    __syncthreads();
    const u32 nv = novf > 128u ? 128u : novf;
    const float inv = 1.0f / 1024.0f;
    for (int i = t; i < 1920; i += 256) {
        const int hx = i / 384;
        const int hy = (i >> 7) % 3;
        const int z  = i & 127;
        float acc = 0.0f;
        #pragma unroll
        for (int sx = 0; sx < 2; ++sx) {
            const int bx = hx - 1 + sx;            // sx=0 -> dx=1 (weight fx)
            if ((unsigned)bx > 3u) continue;
            #pragma unroll
            for (int sy = 0; sy < 2; ++sy) {
                const int by = hy - 1 + sy;
                if ((unsigned)by > 1u) continue;
                #pragma unroll
                for (int sz = 0; sz < 2; ++sz) {
                    const int bz = (z - 1 + sz) & 127;
                    const int c = (((bx << 1) | by) << 7) | bz;
                    const int m = (int)min(cnt[c], (u32)CAP);
                    const int rb = c * CAP;
                    for (int k = 0; k < m; ++k) {
                        const u32 r = rec[rb + k];
                        const float fx = (float)(r & 1023) * inv;
                        const float fy = (float)((r >> 10) & 1023) * inv;
                        const float fz = (float)(r >> 20) * inv;
                        const float wx = sx ? (1.0f - fx) : fx;
                        const float wy = sy ? (1.0f - fy) : fy;
                        const float wz = sz ? (1.0f - fz) : fz;
                        acc += wx * wy * wz;
                    }
                }
            }
        }
        for (u32 j = 0; j < nv; ++j) {
            const u64 o = ovf[j];
            const int c = (int)(o >> 32);
            const int obx = (c >> 8) & 3, oby = (c >> 7) & 1, obz = c & 127;
            const int dx = hx - obx, dy = hy - oby, dz = (z - obz) & 127;
            if ((unsigned)dx < 2u && (unsigned)dy < 2u && dz < 2) {
                const u32 r = (u32)o;
                const float fx = (float)(r & 1023) * inv;
                const float fy = (float)((r >> 10) & 1023) * inv;
                const float fz = (float)(r >> 20) * inv;
                acc += (dx ? fx : 1.0f - fx) * (dy ? fy : 1.0f - fy)
                     * (dz ? fz : 1.0f - fz);
            }
        }
        ST[(size_t)b * 1920 + i] = acc;
    }
}

__global__ __launch_bounds__(256) void readout_kernel(const u64* __restrict__ S,
                                                      const u32* __restrict__ offsets,
                                                      const u32* __restrict__ Abf,
                                                      const u16* __restrict__ Brl,
                                                      const float* __restrict__ vel,
                                                      const float* __restrict__ fdf,
                                                      float* __restrict__ out) {
    __shared__ float2 sxy[1920];
    __shared__ float  szz[1920];
    const int t = threadIdx.x;
    const int b = blockIdx.x;
    const int x0 = (b >> 6) << 2, y0 = (b & 63) << 1;
    for (int i = t; i < 1920; i += 256) {
        const int hx = i / 384;
        const int hy = (i >> 7) % 3;
        const int z = i & 127;
        const int g = (((x0 + hx) & 127) << 14) | (((y0 + hy) & 127) << 7) | z;
        const u32 ab = Abf[g];
        sxy[i] = make_float2(__uint_as_float(ab << 16),
                             __uint_as_float(ab & 0xFFFF0000u));
        szz[i] = bf2f(Brl[g]);
    }
    __syncthreads();
    const float sc = 0.2f / fdf[0];
    const int start = offsets[b], end = offsets[b + 1];
    for (int i = start + t; i < end; i += 256) {
        int iz, lx, ly, n;
        float fx, fy, fz;
        decode(S[i], iz, lx, ly, fx, fy, fz, n);
        const float wx[2] = {1.0f - fx, fx};
        const float wy[2] = {1.0f - fy, fy};
        const float wz[2] = {1.0f - fz, fz};
        float gx = 0.f, gy = 0.f, gz = 0.f;
        #pragma unroll
        for (int dx = 0; dx < 2; ++dx)
            #pragma unroll
            for (int dy = 0; dy < 2; ++dy) {
                const int bi = ((lx + dx) * 3 + (ly + dy)) << 7;
                const float wxy = wx[dx] * wy[dy];
                #pragma unroll
                for (int dz = 0; dz < 2; ++dz) {
                    const int idx2 = bi + ((iz + dz) & 127);
                    const float w = wxy * wz[dz];
                    const float2 a = sxy[idx2];
                    gx += w * a.x;
                    gy += w * a.y;
                    gz += w * szz[idx2];
                }
            }
        out[3 * NPART + 3 * n + 0] = vel[3 * n + 0] + gx * sc;
        out[3 * NPART + 3 * n + 1] = vel[3 * n + 1] + gy * sc;
        out[3 * NPART + 3 * n + 2] = vel[3 * n + 2] + gz * sc;
    }
}

extern "C" void kernel_launch(void* const* d_in, const int* in_sizes, int n_in,
                              void* d_out, int out_size, void* d_ws, size_t ws_size,
                              hipStream_t stream) {
    const float* pos = (const float*)d_in[0];
    const float* vel = (const float*)d_in[1];
    const float* fdf = (const float*)d_in[2];
    float* out = (float*)d_out;

    float2* A  = (float2*)d_ws;            // 16.78 MB complex grid
    float2* B  = A + MESH3;                // 16.78 MB complex grid
    float*  ST = (float*)B;                // 15.7 MB paint staging (dead before mega writes B)
    u32*    Abf = (u32*)B;                 // 8.39 MB bf16x2 A-field (B dead by then)
    u64* S    = (u64*)d_out;                            // 16.78 MB sorted particles
    u16* Brl  = (u16*)((char*)d_out + (MESH3 * 8));     // 4.19 MB bf16 fz field
    u32* cnt     = (u32*)((char*)d_out + (21 << 20));   // 2048
    u32* offsets = cnt + 2048;                          // 2049
    u32* cursors = offsets + 2049;                      // 2048

    hipMemsetAsync(cnt, 0, 2048 * sizeof(u32), stream);
    hist_kernel<<<256, 256, 0, stream>>>(pos, cnt);
    scan_kernel<<<1, 1024, 0, stream>>>(cnt, offsets, cursors);
    scatter_kernel<<<256, 256, 0, stream>>>(pos, cursors, S);

    paint_kernel<<<2048, 256, 0, stream>>>(S, offsets, ST);

    fft_z_fwd_merge<<<1024, 256, 0, stream>>>(ST, A);   // halo merge + fwd z
    fft_y_fwd<<<1024, 256, 0, stream>>>(A);
    fft_x_mega<<<1024, 256, 0, stream>>>(A, B);         // fwd x + filter + inv x (A,B)
    fft_y_inv_dual<<<2048, 256, 0, stream>>>(A, B);     // inv y on both grids
    fft_z_inv_bf16<true><<<1024, 256, 0, stream>>>(B, (void*)Brl);   // B -> bf16 Re
    fft_z_inv_bf16<false><<<1024, 256, 0, stream>>>(A, (void*)Abf);  // A -> bf16x2

    readout_kernel<<<2048, 256, 0, stream>>>(S, offsets, Abf, Brl, vel, fdf, out);
    hipMemcpyAsync(out, pos, (size_t)NPART * 3 * sizeof(float),
                   hipMemcpyDeviceToDevice, stream);
}